// Round 1
// baseline (640.040 us; speedup 1.0000x reference)
//
#include <hip/hip_runtime.h>

// MeanAggregator: out[b, :] = mean_k features[neigh_idx[b,k], :]
// U=1e6, D=128, B=1e5, K=10.  Pure memory-bound gather-reduce.
//
// Layout: 32 threads per output row, each thread owns one float4 (4 floats),
// so one gathered feature row = 32 lanes x 16 B = 512 B, fully coalesced.

#define AGG_D 128
#define AGG_K 10

__global__ __launch_bounds__(256) void MeanAggregator_43946105372917_kernel(
    const float* __restrict__ features,
    const int*   __restrict__ neigh_idx,
    float*       __restrict__ out,
    int B)
{
    const int tid  = blockIdx.x * blockDim.x + threadIdx.x;
    const int row  = tid >> 5;            // 32 threads per output row
    const int col  = (tid & 31) << 2;     // float4 column offset
    if (row >= B) return;

    // Load all K indices first so the K gathers can all be in flight.
    const int* __restrict__ idx_row = neigh_idx + row * AGG_K;
    int idx[AGG_K];
#pragma unroll
    for (int k = 0; k < AGG_K; ++k) idx[k] = idx_row[k];

    float4 acc = make_float4(0.f, 0.f, 0.f, 0.f);
#pragma unroll
    for (int k = 0; k < AGG_K; ++k) {
        const float4 v = *(const float4*)(features + (size_t)idx[k] * AGG_D + col);
        acc.x += v.x; acc.y += v.y; acc.z += v.z; acc.w += v.w;
    }

    const float s = 1.0f / (float)AGG_K;
    float4 r = make_float4(acc.x * s, acc.y * s, acc.z * s, acc.w * s);
    *(float4*)(out + (size_t)row * AGG_D + col) = r;
}

extern "C" void kernel_launch(void* const* d_in, const int* in_sizes, int n_in,
                              void* d_out, int out_size, void* d_ws, size_t ws_size,
                              hipStream_t stream) {
    const float* features  = (const float*)d_in[0];
    const int*   neigh_idx = (const int*)d_in[1];
    float*       out       = (float*)d_out;

    const int B = in_sizes[1] / AGG_K;          // 100000
    const int total_threads = B * 32;           // 32 lanes per row
    const int block = 256;
    const int grid  = (total_threads + block - 1) / block;

    MeanAggregator_43946105372917_kernel<<<grid, block, 0, stream>>>(
        features, neigh_idx, out, B);
}